// Round 2
// baseline (8060.220 us; speedup 1.0000x reference)
//
#include <hip/hip_runtime.h>
#include <cstdint>

#define UNITS 128
#define GATES 512            // 4*UNITS
#define IN_DIM 128
#define BATCH 64
#define SEQ 2048
#define ROWS (BATCH * SEQ)   // 131072

typedef _Float16 f16;
typedef _Float16 f16x2 __attribute__((ext_vector_type(2)));
typedef _Float16 f16x8 __attribute__((ext_vector_type(8)));
typedef float    f32x4 __attribute__((ext_vector_type(4)));

static __device__ __forceinline__ float sigmoid_f(float x) {
    float e = __builtin_amdgcn_exp2f(-1.44269504f * x);
    return __builtin_amdgcn_rcpf(1.0f + e);
}
static __device__ __forceinline__ float tanh_f(float x) {
    float e = __builtin_amdgcn_exp2f(2.8853900817779268f * x);
    return 1.0f - 2.0f * __builtin_amdgcn_rcpf(1.0f + e);
}

// ---------------------------------------------------------------------------
// Kernel 1: WxT[n][k] = (f16)Wx[k][n]  — f32 coalesced read, f16 transpose out
// ---------------------------------------------------------------------------
__global__ void wxt_kernel(const float* __restrict__ W,
                           f16* __restrict__ WxT) {
    int idx = blockIdx.x * 256 + threadIdx.x;     // 0 .. 65535 over Wx (128x512)
    int k = idx >> 9, n = idx & 511;              // coalesced read of W[idx]
    WxT[n * IN_DIM + k] = (f16)W[idx];
}

// ---------------------------------------------------------------------------
// Kernel 2: xp = data @ Wx + b, f16 out (ROWS x 512)
// mfma_f32_16x16x32_f16. WG = 256 thr (4 waves), 128 rows/WG (32/wave).
// A frags: data f32 -> f16 in-register. B frags: WxT f16 (L2-resident).
// A layout: A[m=lane&15][k=quad*8+j]; D: col=lane&15, row=quad*4+reg.
// ---------------------------------------------------------------------------
__global__ __launch_bounds__(256) void xp_gemm(
        const float* __restrict__ A,      // data f32, ROWS x 128
        const f16*  __restrict__ WxT,     // 512 x 128 f16
        const float* __restrict__ bias,   // 512 f32
        f16* __restrict__ xp) {
    const int wave = threadIdx.x >> 6;
    const int lane = threadIdx.x & 63;
    const int m16  = lane & 15;
    const int q    = lane >> 4;
    const int rowBase = blockIdx.x * 128 + wave * 32;

    f16x8 a[2][4];
    #pragma unroll
    for (int mc = 0; mc < 2; ++mc)
        #pragma unroll
        for (int ks = 0; ks < 4; ++ks) {
            const float* p = A + (size_t)(rowBase + mc * 16 + m16) * IN_DIM
                               + ks * 32 + q * 8;
            float4 lo = *(const float4*)p;
            float4 hi = *(const float4*)(p + 4);
            f16x8 v;
            v[0] = (f16)lo.x; v[1] = (f16)lo.y; v[2] = (f16)lo.z; v[3] = (f16)lo.w;
            v[4] = (f16)hi.x; v[5] = (f16)hi.y; v[6] = (f16)hi.z; v[7] = (f16)hi.w;
            a[mc][ks] = v;
        }

    for (int nt = 0; nt < 32; ++nt) {
        f16x8 bfr[4];
        #pragma unroll
        for (int ks = 0; ks < 4; ++ks)
            bfr[ks] = *(const f16x8*)(WxT + (nt * 16 + m16) * IN_DIM + ks * 32 + q * 8);
        f32x4 acc0 = {0.f, 0.f, 0.f, 0.f}, acc1 = {0.f, 0.f, 0.f, 0.f};
        #pragma unroll
        for (int ks = 0; ks < 4; ++ks) {
            acc0 = __builtin_amdgcn_mfma_f32_16x16x32_f16(a[0][ks], bfr[ks], acc0, 0, 0, 0);
            acc1 = __builtin_amdgcn_mfma_f32_16x16x32_f16(a[1][ks], bfr[ks], acc1, 0, 0, 0);
        }
        float bv = bias[nt * 16 + m16];
        #pragma unroll
        for (int r = 0; r < 4; ++r) {
            int row0 = rowBase + q * 4 + r;
            xp[(size_t)row0 * GATES + nt * 16 + m16]        = (f16)(acc0[r] + bv);
            xp[(size_t)(row0 + 16) * GATES + nt * 16 + m16] = (f16)(acc1[r] + bv);
        }
    }
}

// ---------------------------------------------------------------------------
// Kernel 3: sequential scan. 64 WGs (one per sample), 256 threads.
// Thread j owns gate-columns j and j+256; Wh columns in 128 VGPRs (f16x2);
// h broadcast via LDS (double-buffered, b128 same-address reads = free);
// v_dot2_f32_f16 matvec; xp prefetched 2 steps ahead. f32 output.
// ---------------------------------------------------------------------------
template <bool FUSED>
__global__ __launch_bounds__(256, 1) void lstm_scan(
        const float* __restrict__ W,      // 256 x 512 f32
        const float* __restrict__ bias,   // 512 f32 (FUSED only)
        const float* __restrict__ data,   // ROWS x 128 f32 (FUSED only)
        const f16* __restrict__ xp,       // ROWS x 512 f16 (!FUSED)
        float* __restrict__ out) {        // ROWS x 128 f32
    __shared__ __align__(16) f16 h_lds[2][UNITS];
    __shared__ __align__(16) f16 x_lds[2][UNITS];
    __shared__ float z_lds[GATES];

    const int tid = threadIdx.x;
    const int b   = blockIdx.x;
    const int j0  = tid, j1 = tid + 256;

    // Wh columns j0, j1 -> registers as f16 pairs (coalesced f32 reads).
    f16x2 wh0[64], wh1[64];
    #pragma unroll 4
    for (int k = 0; k < 64; ++k) {
        wh0[k] = f16x2{(f16)W[(size_t)(IN_DIM + 2 * k) * GATES + j0],
                       (f16)W[(size_t)(IN_DIM + 2 * k + 1) * GATES + j0]};
        wh1[k] = f16x2{(f16)W[(size_t)(IN_DIM + 2 * k) * GATES + j1],
                       (f16)W[(size_t)(IN_DIM + 2 * k + 1) * GATES + j1]};
    }
    f16x2 wxa[64], wxb[64];
    float bb0 = 0.f, bb1 = 0.f;
    if (FUSED) {
        #pragma unroll 4
        for (int k = 0; k < 64; ++k) {
            wxa[k] = f16x2{(f16)W[(size_t)(2 * k) * GATES + j0],
                           (f16)W[(size_t)(2 * k + 1) * GATES + j0]};
            wxb[k] = f16x2{(f16)W[(size_t)(2 * k) * GATES + j1],
                           (f16)W[(size_t)(2 * k + 1) * GATES + j1]};
        }
        bb0 = bias[j0];
        bb1 = bias[j1];
    }

    float c = 1.0f;                                // reference: c0 = ones
    if (tid < UNITS) h_lds[0][tid] = (f16)0.f;     // h0 = zeros
    if (FUSED && tid < UNITS)
        x_lds[0][tid] = (f16)data[(size_t)b * SEQ * IN_DIM + tid];

    const f16* xp_b = xp + (FUSED ? 0 : (size_t)b * SEQ * GATES);
    // prefetch pipeline, distance 2 (HBM latency ~900cy ≈ 2 steps)
    f16 xA0 = (f16)0.f, xA1 = (f16)0.f, xB0 = (f16)0.f, xB1 = (f16)0.f;
    if (!FUSED) {
        xA0 = xp_b[j0];          xA1 = xp_b[j1];            // t = 0
        xB0 = xp_b[GATES + j0];  xB1 = xp_b[GATES + j1];    // t = 1
    }
    __syncthreads();

    for (int t = 0; t < SEQ; ++t) {
        const int cur = t & 1, nxt = cur ^ 1;
        float xc0, xc1;
        if (!FUSED) {
            xc0 = (float)xA0; xc1 = (float)xA1;
            xA0 = xB0; xA1 = xB1;
            int t2 = (t + 2 < SEQ) ? (t + 2) : (SEQ - 1);   // clamped, no OOB
            xB0 = xp_b[(size_t)t2 * GATES + j0];
            xB1 = xp_b[(size_t)t2 * GATES + j1];
        } else { xc0 = bb0; xc1 = bb1; }

        float a00 = xc0, a01 = 0.f, a10 = xc1, a11 = 0.f;

        if (FUSED) {
            float4 xbuf[16];
            const float4* xsrc = (const float4*)x_lds[cur];
            #pragma unroll
            for (int i = 0; i < 16; ++i) xbuf[i] = xsrc[i];
            const f16x2* xx = (const f16x2*)xbuf;
            #pragma unroll
            for (int k = 0; k < 32; ++k) {
                a00 = __builtin_amdgcn_fdot2(xx[k],      wxa[k],      a00, false);
                a10 = __builtin_amdgcn_fdot2(xx[k],      wxb[k],      a10, false);
                a01 = __builtin_amdgcn_fdot2(xx[k + 32], wxa[k + 32], a01, false);
                a11 = __builtin_amdgcn_fdot2(xx[k + 32], wxb[k + 32], a11, false);
            }
        }

        // h broadcast: 16 x ds_read_b128, same address across lanes (free)
        float4 hbuf[16];
        const float4* hsrc = (const float4*)h_lds[cur];
        #pragma unroll
        for (int i = 0; i < 16; ++i) hbuf[i] = hsrc[i];
        const f16x2* hh = (const f16x2*)hbuf;
        #pragma unroll
        for (int k = 0; k < 32; ++k) {               // 4 independent dot chains
            a00 = __builtin_amdgcn_fdot2(hh[k],      wh0[k],      a00, false);
            a10 = __builtin_amdgcn_fdot2(hh[k],      wh1[k],      a10, false);
            a01 = __builtin_amdgcn_fdot2(hh[k + 32], wh0[k + 32], a01, false);
            a11 = __builtin_amdgcn_fdot2(hh[k + 32], wh1[k + 32], a11, false);
        }
        float z0 = a00 + a01, z1 = a10 + a11;

        // Nonlinearity BEFORE the LDS combine (distributes transcendentals):
        // j0 in [0,256): i/f -> sigmoid. j1: o -> sigmoid (tid<128),
        // g -> tanh (tid>=128). Branch is wave-uniform.
        z_lds[j0] = sigmoid_f(z0);
        if (tid < 128) z_lds[j1] = sigmoid_f(z1);
        else           z_lds[j1] = tanh_f(z1);

        if (FUSED && tid < UNITS) {                  // stage x_{t+1}
            int t1 = (t + 1 < SEQ) ? (t + 1) : t;
            x_lds[nxt][tid] = (f16)data[(size_t)b * SEQ * IN_DIM
                                        + (size_t)t1 * IN_DIM + tid];
        }
        __syncthreads();

        if (tid < UNITS) {
            float si = z_lds[tid], sf = z_lds[tid + 128];
            float so = z_lds[tid + 256], tg = z_lds[tid + 384];
            c = sf * c + si * tg;
            float h = so * tanh_f(c);
            h_lds[nxt][tid] = (f16)h;
            out[((size_t)b * SEQ + t) * UNITS + tid] = h;
        }
        __syncthreads();
    }
}

// ---------------------------------------------------------------------------
extern "C" void kernel_launch(void* const* d_in, const int* in_sizes, int n_in,
                              void* d_out, int out_size, void* d_ws, size_t ws_size,
                              hipStream_t stream) {
    const float* data = (const float*)d_in[0];   // f32 (64,2048,128)
    const float* W    = (const float*)d_in[1];   // f32 (256,512)
    const float* bias = (const float*)d_in[2];   // f32 (512,)
    float* out = (float*)d_out;                  // f32 (64,2048,128)

    const size_t wxt_bytes = (size_t)GATES * IN_DIM * sizeof(f16);  // 128 KiB
    const size_t xp_bytes  = (size_t)ROWS * GATES * sizeof(f16);    // 128 MiB
    if (ws_size >= wxt_bytes + xp_bytes) {
        f16* WxT = (f16*)d_ws;
        f16* xp  = (f16*)((char*)d_ws + wxt_bytes);
        hipLaunchKernelGGL(wxt_kernel, dim3(256), dim3(256), 0, stream, W, WxT);
        hipLaunchKernelGGL(xp_gemm, dim3(ROWS / 128), dim3(256), 0, stream,
                           data, WxT, bias, xp);
        hipLaunchKernelGGL((lstm_scan<false>), dim3(BATCH), dim3(256), 0, stream,
                           W, bias, data, xp, out);
    } else {
        // Workspace too small for xp: fused fallback (Wx also register-resident).
        hipLaunchKernelGGL((lstm_scan<true>), dim3(BATCH), dim3(256), 0, stream,
                           W, bias, data, (const f16*)nullptr, out);
    }
}

// Round 4
// 1487.331 us; speedup vs baseline: 5.4192x; 5.4192x over previous
//
#include <hip/hip_runtime.h>
#include <cstdint>

#define UNITS 128
#define GATES 512            // 4*UNITS
#define IN_DIM 128
#define BATCH 64
#define SEQ 2048
#define ROWS (BATCH * SEQ)   // 131072

typedef _Float16 f16;
typedef _Float16 f16x2 __attribute__((ext_vector_type(2)));
typedef _Float16 f16x8 __attribute__((ext_vector_type(8)));
typedef float    f32x4 __attribute__((ext_vector_type(4)));

static __device__ __forceinline__ float sigmoid_f(float x) {
    float e = __builtin_amdgcn_exp2f(-1.44269504f * x);
    return __builtin_amdgcn_rcpf(1.0f + e);
}
static __device__ __forceinline__ float tanh_f(float x) {
    float e = __builtin_amdgcn_exp2f(2.8853900817779268f * x);
    return 1.0f - 2.0f * __builtin_amdgcn_rcpf(1.0f + e);
}

// ---------------------------------------------------------------------------
// Kernel 1: WxT[n][k] = (f16)Wx[k][n]  — f32 coalesced read, f16 transpose out
// ---------------------------------------------------------------------------
__global__ void wxt_kernel(const float* __restrict__ W,
                           f16* __restrict__ WxT) {
    int idx = blockIdx.x * 256 + threadIdx.x;     // 0 .. 65535 over Wx (128x512)
    int k = idx >> 9, n = idx & 511;              // coalesced read of W[idx]
    WxT[n * IN_DIM + k] = (f16)W[idx];
}

// ---------------------------------------------------------------------------
// Kernel 2: xp = data @ Wx + b, f16 out (ROWS x 512)   [unchanged, verified]
// ---------------------------------------------------------------------------
__global__ __launch_bounds__(256) void xp_gemm(
        const float* __restrict__ A,      // data f32, ROWS x 128
        const f16*  __restrict__ WxT,     // 512 x 128 f16
        const float* __restrict__ bias,   // 512 f32
        f16* __restrict__ xp) {
    const int wave = threadIdx.x >> 6;
    const int lane = threadIdx.x & 63;
    const int m16  = lane & 15;
    const int q    = lane >> 4;
    const int rowBase = blockIdx.x * 128 + wave * 32;

    f16x8 a[2][4];
    #pragma unroll
    for (int mc = 0; mc < 2; ++mc)
        #pragma unroll
        for (int ks = 0; ks < 4; ++ks) {
            const float* p = A + (size_t)(rowBase + mc * 16 + m16) * IN_DIM
                               + ks * 32 + q * 8;
            float4 lo = *(const float4*)p;
            float4 hi = *(const float4*)(p + 4);
            f16x8 v;
            v[0] = (f16)lo.x; v[1] = (f16)lo.y; v[2] = (f16)lo.z; v[3] = (f16)lo.w;
            v[4] = (f16)hi.x; v[5] = (f16)hi.y; v[6] = (f16)hi.z; v[7] = (f16)hi.w;
            a[mc][ks] = v;
        }

    for (int nt = 0; nt < 32; ++nt) {
        f16x8 bfr[4];
        #pragma unroll
        for (int ks = 0; ks < 4; ++ks)
            bfr[ks] = *(const f16x8*)(WxT + (nt * 16 + m16) * IN_DIM + ks * 32 + q * 8);
        f32x4 acc0 = {0.f, 0.f, 0.f, 0.f}, acc1 = {0.f, 0.f, 0.f, 0.f};
        #pragma unroll
        for (int ks = 0; ks < 4; ++ks) {
            acc0 = __builtin_amdgcn_mfma_f32_16x16x32_f16(a[0][ks], bfr[ks], acc0, 0, 0, 0);
            acc1 = __builtin_amdgcn_mfma_f32_16x16x32_f16(a[1][ks], bfr[ks], acc1, 0, 0, 0);
        }
        float bv = bias[nt * 16 + m16];
        #pragma unroll
        for (int r = 0; r < 4; ++r) {
            int row0 = rowBase + q * 4 + r;
            xp[(size_t)row0 * GATES + nt * 16 + m16]        = (f16)(acc0[r] + bv);
            xp[(size_t)(row0 + 16) * GATES + nt * 16 + m16] = (f16)(acc1[r] + bv);
        }
    }
}

// ---------------------------------------------------------------------------
// Kernel 3: sequential scan. 64 WGs (one per sample), 256 threads.
//
// Column ownership (per wave w, lane l):
//   cell j   = w*32 + (l&31)
//   l  < 32  -> cols { j       (i-gate), j+128 (f-gate) }
//   l >= 32  -> cols { j+256   (o-gate), j+384 (g-gate) }
// A cell's 4 gates live in lanes l and l^32 of ONE wave: exchanged with two
// __shfl_xor(...,32) — no z_lds, ONE barrier per step (h double-buffer).
//
// Wh columns in 128 VGPRs (f16x2, fully-unrolled init: partial unroll spills
// the array to scratch — round-2 showed VGPR_Count=32, 7.9 ms).
// h broadcast via 16 x f16x8 LDS reads (same-addr across lanes = free b'cast).
// Pair extraction via vector subscripts (shufflevector needs frontend-constant
// indices — round-3 compile failure).
// ---------------------------------------------------------------------------
template <bool FUSED>
__global__ __launch_bounds__(256, 1) void lstm_scan(
        const float* __restrict__ W,      // 256 x 512 f32
        const float* __restrict__ bias,   // 512 f32 (FUSED only)
        const float* __restrict__ data,   // ROWS x 128 f32 (FUSED only)
        const f16* __restrict__ xp,       // ROWS x 512 f16 (!FUSED)
        float* __restrict__ out) {        // ROWS x 128 f32
    __shared__ __align__(16) f16 h_lds[2][UNITS];
    __shared__ __align__(16) f16 x_lds[2][UNITS];

    const int tid  = threadIdx.x;
    const int b    = blockIdx.x;
    const int wave = tid >> 6;
    const int lane = tid & 63;
    const int half = lane >> 5;                 // 0: {i,f}  1: {o,g}
    const int cell = wave * 32 + (lane & 31);   // j in [0,128)
    const int c0   = cell + half * 256;         // i_j  or  o_j
    const int c1   = c0 + 128;                  // f_j  or  g_j

    // Wh columns c0, c1 -> 128 VGPRs as f16 pairs. FULLY unrolled (constant
    // indices) so SROA keeps the arrays in registers.
    f16x2 wh0[64], wh1[64];
    #pragma unroll
    for (int k = 0; k < 64; ++k) {
        wh0[k] = f16x2{(f16)W[(size_t)(IN_DIM + 2 * k) * GATES + c0],
                       (f16)W[(size_t)(IN_DIM + 2 * k + 1) * GATES + c0]};
        wh1[k] = f16x2{(f16)W[(size_t)(IN_DIM + 2 * k) * GATES + c1],
                       (f16)W[(size_t)(IN_DIM + 2 * k + 1) * GATES + c1]};
    }
    f16x2 wxa[64], wxb[64];
    float bb0 = 0.f, bb1 = 0.f;
    if (FUSED) {
        #pragma unroll
        for (int k = 0; k < 64; ++k) {
            wxa[k] = f16x2{(f16)W[(size_t)(2 * k) * GATES + c0],
                           (f16)W[(size_t)(2 * k + 1) * GATES + c0]};
            wxb[k] = f16x2{(f16)W[(size_t)(2 * k) * GATES + c1],
                           (f16)W[(size_t)(2 * k + 1) * GATES + c1]};
        }
        bb0 = bias[c0];
        bb1 = bias[c1];
    }

    float c = 1.0f;                                // reference: c0 = ones
    if (tid < UNITS) h_lds[0][tid] = (f16)0.f;     // h0 = zeros
    if (FUSED && tid < UNITS)
        x_lds[0][tid] = (f16)data[(size_t)b * SEQ * IN_DIM + tid];

    const f16* xp_b = xp + (size_t)b * SEQ * GATES;
    // xp prefetch pipeline, distance 2 (HBM latency ~900 cy ≈ 2 steps)
    f16 xA0 = (f16)0.f, xA1 = (f16)0.f, xB0 = (f16)0.f, xB1 = (f16)0.f;
    if (!FUSED) {
        xA0 = xp_b[c0];          xA1 = xp_b[c1];            // t = 0
        xB0 = xp_b[GATES + c0];  xB1 = xp_b[GATES + c1];    // t = 1
    }
    __syncthreads();

    for (int t = 0; t < SEQ; ++t) {
        const int cur = t & 1, nxt = cur ^ 1;
        float xc0, xc1;
        if (!FUSED) {
            xc0 = (float)xA0; xc1 = (float)xA1;
            xA0 = xB0; xA1 = xB1;
            int t2 = (t + 2 < SEQ) ? (t + 2) : (SEQ - 1);   // clamped, no OOB
            xB0 = xp_b[(size_t)t2 * GATES + c0];
            xB1 = xp_b[(size_t)t2 * GATES + c1];
        } else { xc0 = bb0; xc1 = bb1; }

        float a00 = xc0, a01 = 0.f, a10 = xc1, a11 = 0.f;

        if (FUSED) {
            const f16x8* xsrc = (const f16x8*)x_lds[cur];
            f16x8 xb[16];
            #pragma unroll
            for (int i = 0; i < 16; ++i) xb[i] = xsrc[i];
            #pragma unroll
            for (int i = 0; i < 16; ++i)
                #pragma unroll
                for (int p = 0; p < 4; ++p) {
                    const int k = 4 * i + p;
                    f16x2 xpair = f16x2{xb[i][2 * p], xb[i][2 * p + 1]};
                    if (k < 32) {
                        a00 = __builtin_amdgcn_fdot2(xpair, wxa[k], a00, false);
                        a10 = __builtin_amdgcn_fdot2(xpair, wxb[k], a10, false);
                    } else {
                        a01 = __builtin_amdgcn_fdot2(xpair, wxa[k], a01, false);
                        a11 = __builtin_amdgcn_fdot2(xpair, wxb[k], a11, false);
                    }
                }
        }

        // h broadcast: 16 x 16B LDS reads, same address across all lanes.
        const f16x8* hsrc = (const f16x8*)h_lds[cur];
        f16x8 hb[16];
        #pragma unroll
        for (int i = 0; i < 16; ++i) hb[i] = hsrc[i];
        #pragma unroll
        for (int i = 0; i < 16; ++i)
            #pragma unroll
            for (int p = 0; p < 4; ++p) {
                const int k = 4 * i + p;                  // pair index 0..63
                f16x2 hp = f16x2{hb[i][2 * p], hb[i][2 * p + 1]};
                if (k < 32) {                             // 4 independent chains
                    a00 = __builtin_amdgcn_fdot2(hp, wh0[k], a00, false);
                    a10 = __builtin_amdgcn_fdot2(hp, wh1[k], a10, false);
                } else {
                    a01 = __builtin_amdgcn_fdot2(hp, wh0[k], a01, false);
                    a11 = __builtin_amdgcn_fdot2(hp, wh1[k], a11, false);
                }
            }
        float z0 = a00 + a01, z1 = a10 + a11;

        // half==0: z0=i, z1=f (both sigmoid). half==1: z0=o (sigmoid), z1=g (tanh)
        float s0 = sigmoid_f(z0);
        float s1 = (half == 0) ? sigmoid_f(z1) : tanh_f(z1);
        float p0 = __shfl_xor(s0, 32, 64);   // partner's first  (o or i)
        float p1 = __shfl_xor(s1, 32, 64);   // partner's second (g or f)

        if (half == 0) {
            // this lane: s0=sig(i), s1=sig(f); partner: p0=sig(o), p1=tanh(g)
            c = s1 * c + s0 * p1;
            float h = p0 * tanh_f(c);
            h_lds[nxt][cell] = (f16)h;
            out[((size_t)b * SEQ + t) * UNITS + cell] = h;
        }

        if (FUSED && tid < UNITS) {                  // stage x_{t+1}
            int t1 = (t + 1 < SEQ) ? (t + 1) : t;
            x_lds[nxt][tid] = (f16)data[(size_t)b * SEQ * IN_DIM
                                        + (size_t)t1 * IN_DIM + tid];
        }
        __syncthreads();     // h_lds[nxt] visible; single barrier per step
    }
}

// ---------------------------------------------------------------------------
extern "C" void kernel_launch(void* const* d_in, const int* in_sizes, int n_in,
                              void* d_out, int out_size, void* d_ws, size_t ws_size,
                              hipStream_t stream) {
    const float* data = (const float*)d_in[0];   // f32 (64,2048,128)
    const float* W    = (const float*)d_in[1];   // f32 (256,512)
    const float* bias = (const float*)d_in[2];   // f32 (512,)
    float* out = (float*)d_out;                  // f32 (64,2048,128)

    const size_t wxt_bytes = (size_t)GATES * IN_DIM * sizeof(f16);  // 128 KiB
    const size_t xp_bytes  = (size_t)ROWS * GATES * sizeof(f16);    // 128 MiB
    if (ws_size >= wxt_bytes + xp_bytes) {
        f16* WxT = (f16*)d_ws;
        f16* xp  = (f16*)((char*)d_ws + wxt_bytes);
        hipLaunchKernelGGL(wxt_kernel, dim3(256), dim3(256), 0, stream, W, WxT);
        hipLaunchKernelGGL(xp_gemm, dim3(ROWS / 128), dim3(256), 0, stream,
                           data, WxT, bias, xp);
        hipLaunchKernelGGL((lstm_scan<false>), dim3(BATCH), dim3(256), 0, stream,
                           W, bias, data, xp, out);
    } else {
        // Workspace too small for xp: fused fallback (Wx also register-resident).
        hipLaunchKernelGGL((lstm_scan<true>), dim3(BATCH), dim3(256), 0, stream,
                           W, bias, data, (const f16*)nullptr, out);
    }
}

// Round 5
// 1356.452 us; speedup vs baseline: 5.9421x; 1.0965x over previous
//
#include <hip/hip_runtime.h>
#include <cstdint>

#define UNITS 128
#define GATES 512            // 4*UNITS
#define IN_DIM 128
#define BATCH 64
#define SEQ 2048
#define ROWS (BATCH * SEQ)   // 131072

typedef _Float16 f16;
typedef _Float16 f16x2 __attribute__((ext_vector_type(2)));
typedef _Float16 f16x8 __attribute__((ext_vector_type(8)));
typedef float    f32x4 __attribute__((ext_vector_type(4)));

static __device__ __forceinline__ float sigmoid_f(float x) {
    float e = __builtin_amdgcn_exp2f(-1.44269504f * x);
    return __builtin_amdgcn_rcpf(1.0f + e);
}
static __device__ __forceinline__ float tanh_f(float x) {
    float e = __builtin_amdgcn_exp2f(2.8853900817779268f * x);
    return 1.0f - 2.0f * __builtin_amdgcn_rcpf(1.0f + e);
}

// Workgroup barrier that orders LDS only: skips __syncthreads()'s
// s_waitcnt vmcnt(0), which would serialize the out[] store retirement and
// the xp prefetch into every step (round-4: ~1542 cy/step, ~690 busy).
static __device__ __forceinline__ void lds_barrier() {
    __asm__ volatile("s_waitcnt lgkmcnt(0)\n\ts_barrier" ::: "memory");
}

// ---------------------------------------------------------------------------
// Kernel 1: WxT[n][k] = (f16)Wx[k][n]  — f32 coalesced read, f16 transpose out
// ---------------------------------------------------------------------------
__global__ void wxt_kernel(const float* __restrict__ W,
                           f16* __restrict__ WxT) {
    int idx = blockIdx.x * 256 + threadIdx.x;     // 0 .. 65535 over Wx (128x512)
    int k = idx >> 9, n = idx & 511;              // coalesced read of W[idx]
    WxT[n * IN_DIM + k] = (f16)W[idx];
}

// ---------------------------------------------------------------------------
// Kernel 2: xp = data @ Wx + b, f16 out (ROWS x 512)   [unchanged, verified]
// ---------------------------------------------------------------------------
__global__ __launch_bounds__(256) void xp_gemm(
        const float* __restrict__ A,      // data f32, ROWS x 128
        const f16*  __restrict__ WxT,     // 512 x 128 f16
        const float* __restrict__ bias,   // 512 f32
        f16* __restrict__ xp) {
    const int wave = threadIdx.x >> 6;
    const int lane = threadIdx.x & 63;
    const int m16  = lane & 15;
    const int q    = lane >> 4;
    const int rowBase = blockIdx.x * 128 + wave * 32;

    f16x8 a[2][4];
    #pragma unroll
    for (int mc = 0; mc < 2; ++mc)
        #pragma unroll
        for (int ks = 0; ks < 4; ++ks) {
            const float* p = A + (size_t)(rowBase + mc * 16 + m16) * IN_DIM
                               + ks * 32 + q * 8;
            float4 lo = *(const float4*)p;
            float4 hi = *(const float4*)(p + 4);
            f16x8 v;
            v[0] = (f16)lo.x; v[1] = (f16)lo.y; v[2] = (f16)lo.z; v[3] = (f16)lo.w;
            v[4] = (f16)hi.x; v[5] = (f16)hi.y; v[6] = (f16)hi.z; v[7] = (f16)hi.w;
            a[mc][ks] = v;
        }

    for (int nt = 0; nt < 32; ++nt) {
        f16x8 bfr[4];
        #pragma unroll
        for (int ks = 0; ks < 4; ++ks)
            bfr[ks] = *(const f16x8*)(WxT + (nt * 16 + m16) * IN_DIM + ks * 32 + q * 8);
        f32x4 acc0 = {0.f, 0.f, 0.f, 0.f}, acc1 = {0.f, 0.f, 0.f, 0.f};
        #pragma unroll
        for (int ks = 0; ks < 4; ++ks) {
            acc0 = __builtin_amdgcn_mfma_f32_16x16x32_f16(a[0][ks], bfr[ks], acc0, 0, 0, 0);
            acc1 = __builtin_amdgcn_mfma_f32_16x16x32_f16(a[1][ks], bfr[ks], acc1, 0, 0, 0);
        }
        float bv = bias[nt * 16 + m16];
        #pragma unroll
        for (int r = 0; r < 4; ++r) {
            int row0 = rowBase + q * 4 + r;
            xp[(size_t)row0 * GATES + nt * 16 + m16]        = (f16)(acc0[r] + bv);
            xp[(size_t)(row0 + 16) * GATES + nt * 16 + m16] = (f16)(acc1[r] + bv);
        }
    }
}

// ---------------------------------------------------------------------------
// Kernel 3: sequential scan. 64 WGs (one per sample), 256 threads.
//
// Column ownership (per wave w, lane l):
//   cell j   = w*32 + (l&31)
//   l  < 32  -> cols { j       (i-gate), j+128 (f-gate) }
//   l >= 32  -> cols { j+256   (o-gate), j+384 (g-gate) }
// A cell's 4 gates live in lanes l and l^32 of ONE wave: exchanged with two
// __shfl_xor(...,32) — no z_lds, ONE lds_barrier per step (h double-buffer).
//
// Wh columns in 128 VGPRs (f16x2, fully-unrolled init; partial unroll spills
// to scratch — round 2: VGPR=32, 7.9 ms).
// h broadcast: 16 x b128 LDS reads as uint4; f16x2 pairs extracted with
// __builtin_bit_cast of the 32-bit components (VGPR aliasing, zero VALU —
// round 4's elementwise f16x2{a,b} ctor emitted ~128 pack insts/step).
// ---------------------------------------------------------------------------
template <bool FUSED>
__global__ __launch_bounds__(256, 1) void lstm_scan(
        const float* __restrict__ W,      // 256 x 512 f32
        const float* __restrict__ bias,   // 512 f32 (FUSED only)
        const float* __restrict__ data,   // ROWS x 128 f32 (FUSED only)
        const f16* __restrict__ xp,       // ROWS x 512 f16 (!FUSED)
        float* __restrict__ out) {        // ROWS x 128 f32
    __shared__ __align__(16) f16 h_lds[2][UNITS];
    __shared__ __align__(16) f16 x_lds[2][UNITS];

    const int tid  = threadIdx.x;
    const int b    = blockIdx.x;
    const int wave = tid >> 6;
    const int lane = tid & 63;
    const int half = lane >> 5;                 // 0: {i,f}  1: {o,g}
    const int cell = wave * 32 + (lane & 31);   // j in [0,128)
    const int c0   = cell + half * 256;         // i_j  or  o_j
    const int c1   = c0 + 128;                  // f_j  or  g_j

    // Wh columns c0, c1 -> 128 VGPRs as f16 pairs. FULLY unrolled.
    f16x2 wh0[64], wh1[64];
    #pragma unroll
    for (int k = 0; k < 64; ++k) {
        wh0[k] = f16x2{(f16)W[(size_t)(IN_DIM + 2 * k) * GATES + c0],
                       (f16)W[(size_t)(IN_DIM + 2 * k + 1) * GATES + c0]};
        wh1[k] = f16x2{(f16)W[(size_t)(IN_DIM + 2 * k) * GATES + c1],
                       (f16)W[(size_t)(IN_DIM + 2 * k + 1) * GATES + c1]};
    }
    f16x2 wxa[64], wxb[64];
    float bb0 = 0.f, bb1 = 0.f;
    if (FUSED) {
        #pragma unroll
        for (int k = 0; k < 64; ++k) {
            wxa[k] = f16x2{(f16)W[(size_t)(2 * k) * GATES + c0],
                           (f16)W[(size_t)(2 * k + 1) * GATES + c0]};
            wxb[k] = f16x2{(f16)W[(size_t)(2 * k) * GATES + c1],
                           (f16)W[(size_t)(2 * k + 1) * GATES + c1]};
        }
        bb0 = bias[c0];
        bb1 = bias[c1];
    }

    float c = 1.0f;                                // reference: c0 = ones
    if (tid < UNITS) h_lds[0][tid] = (f16)0.f;     // h0 = zeros
    if (FUSED && tid < UNITS)
        x_lds[0][tid] = (f16)data[(size_t)b * SEQ * IN_DIM + tid];

    const f16* xp_b = xp + (size_t)b * SEQ * GATES;
    // xp prefetch pipeline, distance 2 (HBM latency ~900 cy ≈ 2 steps)
    f16 xA0 = (f16)0.f, xA1 = (f16)0.f, xB0 = (f16)0.f, xB1 = (f16)0.f;
    if (!FUSED) {
        xA0 = xp_b[c0];          xA1 = xp_b[c1];            // t = 0
        xB0 = xp_b[GATES + c0];  xB1 = xp_b[GATES + c1];    // t = 1
    }
    __syncthreads();     // once, before the loop: full sync is fine here

    for (int t = 0; t < SEQ; ++t) {
        const int cur = t & 1, nxt = cur ^ 1;
        float xc0, xc1;
        if (!FUSED) {
            xc0 = (float)xA0; xc1 = (float)xA1;
            xA0 = xB0; xA1 = xB1;
            int t2 = (t + 2 < SEQ) ? (t + 2) : (SEQ - 1);   // clamped, no OOB
            xB0 = xp_b[(size_t)t2 * GATES + c0];
            xB1 = xp_b[(size_t)t2 * GATES + c1];
        } else { xc0 = bb0; xc1 = bb1; }

        float a00 = xc0, a01 = 0.f, a10 = xc1, a11 = 0.f;

        if (FUSED) {
            const uint4* xsrc = (const uint4*)(&x_lds[cur][0]);
            uint4 xb[16];
            #pragma unroll
            for (int i = 0; i < 16; ++i) xb[i] = xsrc[i];
            #pragma unroll
            for (int i = 0; i < 16; ++i) {
                f16x2 p0 = __builtin_bit_cast(f16x2, xb[i].x);
                f16x2 p1 = __builtin_bit_cast(f16x2, xb[i].y);
                f16x2 p2 = __builtin_bit_cast(f16x2, xb[i].z);
                f16x2 p3 = __builtin_bit_cast(f16x2, xb[i].w);
                const int k = 4 * i;
                if (i < 8) {
                    a00 = __builtin_amdgcn_fdot2(p0, wxa[k],     a00, false);
                    a10 = __builtin_amdgcn_fdot2(p0, wxb[k],     a10, false);
                    a00 = __builtin_amdgcn_fdot2(p1, wxa[k + 1], a00, false);
                    a10 = __builtin_amdgcn_fdot2(p1, wxb[k + 1], a10, false);
                    a00 = __builtin_amdgcn_fdot2(p2, wxa[k + 2], a00, false);
                    a10 = __builtin_amdgcn_fdot2(p2, wxb[k + 2], a10, false);
                    a00 = __builtin_amdgcn_fdot2(p3, wxa[k + 3], a00, false);
                    a10 = __builtin_amdgcn_fdot2(p3, wxb[k + 3], a10, false);
                } else {
                    a01 = __builtin_amdgcn_fdot2(p0, wxa[k],     a01, false);
                    a11 = __builtin_amdgcn_fdot2(p0, wxb[k],     a11, false);
                    a01 = __builtin_amdgcn_fdot2(p1, wxa[k + 1], a01, false);
                    a11 = __builtin_amdgcn_fdot2(p1, wxb[k + 1], a11, false);
                    a01 = __builtin_amdgcn_fdot2(p2, wxa[k + 2], a01, false);
                    a11 = __builtin_amdgcn_fdot2(p2, wxb[k + 2], a11, false);
                    a01 = __builtin_amdgcn_fdot2(p3, wxa[k + 3], a01, false);
                    a11 = __builtin_amdgcn_fdot2(p3, wxb[k + 3], a11, false);
                }
            }
        }

        // h broadcast: 16 x 16B LDS reads, same address across all lanes.
        {
            const uint4* hsrc = (const uint4*)(&h_lds[cur][0]);
            uint4 hb[16];
            #pragma unroll
            for (int i = 0; i < 16; ++i) hb[i] = hsrc[i];
            #pragma unroll
            for (int i = 0; i < 16; ++i) {
                f16x2 p0 = __builtin_bit_cast(f16x2, hb[i].x);
                f16x2 p1 = __builtin_bit_cast(f16x2, hb[i].y);
                f16x2 p2 = __builtin_bit_cast(f16x2, hb[i].z);
                f16x2 p3 = __builtin_bit_cast(f16x2, hb[i].w);
                const int k = 4 * i;
                if (i < 8) {                     // 4 independent chains
                    a00 = __builtin_amdgcn_fdot2(p0, wh0[k],     a00, false);
                    a10 = __builtin_amdgcn_fdot2(p0, wh1[k],     a10, false);
                    a00 = __builtin_amdgcn_fdot2(p1, wh0[k + 1], a00, false);
                    a10 = __builtin_amdgcn_fdot2(p1, wh1[k + 1], a10, false);
                    a00 = __builtin_amdgcn_fdot2(p2, wh0[k + 2], a00, false);
                    a10 = __builtin_amdgcn_fdot2(p2, wh1[k + 2], a10, false);
                    a00 = __builtin_amdgcn_fdot2(p3, wh0[k + 3], a00, false);
                    a10 = __builtin_amdgcn_fdot2(p3, wh1[k + 3], a10, false);
                } else {
                    a01 = __builtin_amdgcn_fdot2(p0, wh0[k],     a01, false);
                    a11 = __builtin_amdgcn_fdot2(p0, wh1[k],     a11, false);
                    a01 = __builtin_amdgcn_fdot2(p1, wh0[k + 1], a01, false);
                    a11 = __builtin_amdgcn_fdot2(p1, wh1[k + 1], a11, false);
                    a01 = __builtin_amdgcn_fdot2(p2, wh0[k + 2], a01, false);
                    a11 = __builtin_amdgcn_fdot2(p2, wh1[k + 2], a11, false);
                    a01 = __builtin_amdgcn_fdot2(p3, wh0[k + 3], a01, false);
                    a11 = __builtin_amdgcn_fdot2(p3, wh1[k + 3], a11, false);
                }
            }
        }
        float z0 = a00 + a01, z1 = a10 + a11;

        // half==0: z0=i, z1=f (both sigmoid). half==1: z0=o (sigmoid), z1=g (tanh)
        float s0 = sigmoid_f(z0);
        float s1 = (half == 0) ? sigmoid_f(z1) : tanh_f(z1);
        float p0 = __shfl_xor(s0, 32, 64);   // partner's first  (o or i)
        float p1 = __shfl_xor(s1, 32, 64);   // partner's second (g or f)

        if (half == 0) {
            // this lane: s0=sig(i), s1=sig(f); partner: p0=sig(o), p1=tanh(g)
            c = s1 * c + s0 * p1;
            float h = p0 * tanh_f(c);
            h_lds[nxt][cell] = (f16)h;
            out[((size_t)b * SEQ + t) * UNITS + cell] = h;
        }

        if (FUSED && tid < UNITS) {                  // stage x_{t+1}
            int t1 = (t + 1 < SEQ) ? (t + 1) : t;
            x_lds[nxt][tid] = (f16)data[(size_t)b * SEQ * IN_DIM
                                        + (size_t)t1 * IN_DIM + tid];
        }
        lds_barrier();   // LDS-only ordering: no vmcnt(0) drain per step
    }
}

// ---------------------------------------------------------------------------
extern "C" void kernel_launch(void* const* d_in, const int* in_sizes, int n_in,
                              void* d_out, int out_size, void* d_ws, size_t ws_size,
                              hipStream_t stream) {
    const float* data = (const float*)d_in[0];   // f32 (64,2048,128)
    const float* W    = (const float*)d_in[1];   // f32 (256,512)
    const float* bias = (const float*)d_in[2];   // f32 (512,)
    float* out = (float*)d_out;                  // f32 (64,2048,128)

    const size_t wxt_bytes = (size_t)GATES * IN_DIM * sizeof(f16);  // 128 KiB
    const size_t xp_bytes  = (size_t)ROWS * GATES * sizeof(f16);    // 128 MiB
    if (ws_size >= wxt_bytes + xp_bytes) {
        f16* WxT = (f16*)d_ws;
        f16* xp  = (f16*)((char*)d_ws + wxt_bytes);
        hipLaunchKernelGGL(wxt_kernel, dim3(256), dim3(256), 0, stream, W, WxT);
        hipLaunchKernelGGL(xp_gemm, dim3(ROWS / 128), dim3(256), 0, stream,
                           data, WxT, bias, xp);
        hipLaunchKernelGGL((lstm_scan<false>), dim3(BATCH), dim3(256), 0, stream,
                           W, bias, data, xp, out);
    } else {
        // Workspace too small for xp: fused fallback (Wx also register-resident).
        hipLaunchKernelGGL((lstm_scan<true>), dim3(BATCH), dim3(256), 0, stream,
                           W, bias, data, (const f16*)nullptr, out);
    }
}